// Round 12
// baseline (115.293 us; speedup 1.0000x reference)
//
#include <hip/hip_runtime.h>
#include <cstdint>

typedef __attribute__((ext_vector_type(8))) short bf16x8_t;
typedef __attribute__((ext_vector_type(4))) float f32x4_t;
typedef __attribute__((ext_vector_type(16))) float f32x16_t;

#define T_SEQ 2048
#define NHEAD 16
#define CDIM  1024

__device__ __forceinline__ unsigned short f2bf(float f) {
  union { float f; unsigned u; } v; v.f = f;
  unsigned r = v.u + 0x7FFFu + ((v.u >> 16) & 1u);
  return (unsigned short)(r >> 16);
}

__device__ __forceinline__ float fast_exp2(float x) {
#if __has_builtin(__builtin_amdgcn_exp2f)
  return __builtin_amdgcn_exp2f(x);
#else
  return __expf(x * 0.6931471805599453f);
#endif
}

// pack two f32 -> one u32 of 2 bf16 (RNE), src0 -> low half
__device__ __forceinline__ unsigned cvtpk(float lo, float hi) {
  unsigned r;
  asm("v_cvt_pk_bf16_f32 %0, %1, %2" : "=v"(r) : "v"(lo), "v"(hi));
  return r;
}
// a' = [a_lo ; b_lo], b' = [a_hi ; b_hi]  (v_permlane32_swap)
#define PLSWAP(a, b) asm("v_permlane32_swap_b32 %0, %1" : "+v"(a), "+v"(b))

__device__ __forceinline__ void gload_lds16(const void* g, void* l) {
  typedef const uint32_t __attribute__((address_space(1)))* gp_t;
  typedef uint32_t __attribute__((address_space(3)))* lp_t;
  __builtin_amdgcn_global_load_lds((gp_t)(uintptr_t)g, (lp_t)(uint32_t)(uintptr_t)l, 16, 0, 0);
}

// ---------------- f32 -> bf16 elementwise ----------------
__global__ void conv_bf16_kernel(const float* __restrict__ in,
                                 unsigned short* __restrict__ out, int n4) {
  int i = blockIdx.x * blockDim.x + threadIdx.x;
  if (i >= n4) return;
  float4 v = ((const float4*)in)[i];
  ushort4 o;
  o.x = f2bf(v.x); o.y = f2bf(v.y); o.z = f2bf(v.z); o.w = f2bf(v.w);
  ((ushort4*)out)[i] = o;
}

// ---------------- transpose f32 [R][C] -> bf16 [C][R] ----------------
__global__ void transpose_bf16_kernel(const float* __restrict__ W,
                                      unsigned short* __restrict__ WT, int R, int C) {
  __shared__ unsigned short tile[64][65];
  const int c0 = blockIdx.x * 64, r0 = blockIdx.y * 64;
  const int t = threadIdx.x;
  #pragma unroll
  for (int i = 0; i < 16; i++) {
    int idx = i * 256 + t;
    int r = idx >> 6, c = idx & 63;
    tile[r][c] = f2bf(W[(size_t)(r0 + r) * C + c0 + c]);
  }
  __syncthreads();
  #pragma unroll
  for (int i = 0; i < 16; i++) {
    int idx = i * 256 + t;
    int c = idx >> 6, r = idx & 63;
    WT[(size_t)(c0 + c) * R + r0 + r] = tile[r][c];
  }
}

// ---------------- GEMM v3 (R10, proven): conflict-free LDS XOR swizzle -------
// MODE 0 (QKV): 128x128 tile, grid 24x32. MODE 1 (proj): 128x64, grid 16x32.
template <int MODE>
__global__ void gemm_bt_kernel(const unsigned short* __restrict__ A,
                               const unsigned short* __restrict__ Bt,
                               const float* __restrict__ bias,
                               unsigned short* __restrict__ q_out,
                               unsigned short* __restrict__ k_out,
                               unsigned short* __restrict__ v_out,
                               float* __restrict__ c_out) {
  constexpr int K = 1024;
  constexpr int TN = (MODE == 0) ? 128 : 64;
  constexpr int NF = TN / 32;          // per-wave n fragments
  const int t = threadIdx.x;
  const int w = t >> 6, l = t & 63;
  const int lr = l & 15, lg = l >> 4;
  const int wr = w >> 1, wc = w & 1;
  const int m0 = blockIdx.y * 128, n0 = blockIdx.x * TN;

  __shared__ __align__(16) unsigned short As[128 * 64];
  __shared__ __align__(16) unsigned short Bs[TN * 64];

  f32x4_t acc[4][NF];
  #pragma unroll
  for (int mi = 0; mi < 4; mi++)
    #pragma unroll
    for (int ni = 0; ni < NF; ni++)
      acc[mi][ni] = (f32x4_t){0.f, 0.f, 0.f, 0.f};

  const int srow = t >> 3;                       // 0..31
  const int sj   = t & 7;                        // 16B chunk
  const int scol = (sj ^ (srow & 7)) * 8;        // pre-swizzled global col
  const int ldst = srow * 64 + sj * 8;           // linear LDS dest
  const size_t abase = (size_t)(m0 + srow) * K + scol;
  const size_t bbase = (size_t)(n0 + srow) * K + scol;

  for (int k0 = 0; k0 < K; k0 += 64) {
    __syncthreads();
    #pragma unroll
    for (int i = 0; i < 4; i++)
      gload_lds16(A + abase + (size_t)i * 32 * K + k0, &As[i * 32 * 64 + ldst]);
    #pragma unroll
    for (int i = 0; i < TN / 32; i++)
      gload_lds16(Bt + bbase + (size_t)i * 32 * K + k0, &Bs[i * 32 * 64 + ldst]);
    __syncthreads();
    #pragma unroll
    for (int ks = 0; ks < 2; ks++) {
      bf16x8_t af[4], bfr[NF];
      #pragma unroll
      for (int mi = 0; mi < 4; mi++) {
        const int row = wr * 64 + mi * 16 + lr;
        af[mi] = *(const bf16x8_t*)&As[row * 64 + (((ks * 4 + lg) ^ (row & 7)) << 3)];
      }
      #pragma unroll
      for (int ni = 0; ni < NF; ni++) {
        const int row = wc * (TN / 2) + ni * 16 + lr;
        bfr[ni] = *(const bf16x8_t*)&Bs[row * 64 + (((ks * 4 + lg) ^ (row & 7)) << 3)];
      }
      #pragma unroll
      for (int mi = 0; mi < 4; mi++)
        #pragma unroll
        for (int ni = 0; ni < NF; ni++)
          acc[mi][ni] = __builtin_amdgcn_mfma_f32_16x16x32_bf16(af[mi], bfr[ni], acc[mi][ni], 0, 0, 0);
    }
  }

  if (MODE == 0) {
    const float QSCALE = 0.125f * 1.4426950408889634f;  // 1/sqrt(64) * log2(e)
    #pragma unroll
    for (int ni = 0; ni < NF; ni++) {
      const int n = n0 + wc * 64 + ni * 16 + lr;
      const float bv = bias[n];
      const int s = n >> 10;           // 0:q 1:k 2:v
      const int hh = (n >> 6) & 15;
      const int d = n & 63;
      #pragma unroll
      for (int mi = 0; mi < 4; mi++) {
        const int mbase = m0 + wr * 64 + mi * 16 + lg * 4;
        const int batch = mbase >> 11;
        const int tt = mbase & 2047;
        const int bhh = batch * NHEAD + hh;
        if (s == 0) {
          #pragma unroll
          for (int r = 0; r < 4; r++)
            q_out[((size_t)bhh * T_SEQ + tt + r) * 64 + d] = f2bf((acc[mi][ni][r] + bv) * QSCALE);
        } else if (s == 1) {
          #pragma unroll
          for (int r = 0; r < 4; r++) {
            const int dsw = ((((d >> 3) ^ ((tt + r) & 7)) << 3) | (d & 7));
            k_out[((size_t)bhh * T_SEQ + tt + r) * 64 + dsw] = f2bf(acc[mi][ni][r] + bv);
          }
        } else {
          ushort4 pk;
          pk.x = f2bf(acc[mi][ni][0] + bv);
          pk.y = f2bf(acc[mi][ni][1] + bv);
          pk.z = f2bf(acc[mi][ni][2] + bv);
          pk.w = f2bf(acc[mi][ni][3] + bv);
          const int c2 = (((tt >> 3) & 7) ^ (d & 7));
          const int tt2 = (tt & ~63) | (c2 << 3) | (tt & 7);
          *(ushort4*)&v_out[((size_t)bhh * 64 + d) * T_SEQ + tt2] = pk;
        }
      }
    }
  } else {
    #pragma unroll
    for (int ni = 0; ni < NF; ni++) {
      const int n = n0 + wc * 32 + ni * 16 + lr;
      const float bv = bias[n];
      #pragma unroll
      for (int mi = 0; mi < 4; mi++) {
        const int m = m0 + wr * 64 + mi * 16 + lg * 4;
        #pragma unroll
        for (int r = 0; r < 4; r++)
          c_out[(size_t)(m + r) * 1024 + n] = acc[mi][ni][r] + bv;
      }
    }
  }
}

// ---------------- causal flash attention v9 ----------------
// LDS-traffic-halved: each wave owns 64 q-rows (two 32-row groups g).
// Every K/V fragment ds_read now feeds TWO MFMAs (g=0,1) -> reads/MFMA
// drop 1.0 -> 0.5, halving pressure on the per-CU LDS pipe (the measured
// binding resource). Block = 128 thr (2 waves x 64 rows = 128-row strip);
// grid 512 (16 strips x 32 bh), heavy-first per XCD. In-register P via
// cvt_pk + permlane32_swap per group; no-max exp2 softmax (v6 math).
__global__ __launch_bounds__(128, 2)
void attn_kernel(const unsigned short* __restrict__ Qb,
                 const unsigned short* __restrict__ Kswz,
                 const unsigned short* __restrict__ Vswz,
                 unsigned short* __restrict__ O) {
  const int b0 = blockIdx.x;                 // 0..511
  const int xcd = b0 & 7;
  const int i = b0 >> 3;                     // 0..63 within xcd
  const int bh = xcd * 4 + (i & 3);          // 4 heads per XCD (L2 locality)
  const int strip = 15 - (i >> 2);           // heavy strips first
  const int batch = bh >> 4, h = bh & 15;
  const int q0 = strip * 128;
  const int nT = 2 * strip + 2;

  const int t = threadIdx.x;
  const int w = t >> 6, l = t & 63;
  const int q31 = l & 31, hi = l >> 5;

  __shared__ __align__(16) unsigned short Ks[2][64 * 64];
  __shared__ __align__(16) unsigned short Vs[2][64 * 64];

  const size_t kvbase = (size_t)bh * T_SEQ;

  // 128 threads stage the 64x64 K and V tiles (verbatim copy of pre-swizzled
  // global rows; LDS dest wave-uniform base + lane*16B)
  auto stage = [&](int buf, int kv0) {
    #pragma unroll
    for (int i2 = 0; i2 < 4; i2++) {
      const int flat = i2 * 128 + t;
      const int row = flat >> 3, ch = flat & 7;
      gload_lds16(Kswz + (kvbase + kv0 + row) * 64 + ch * 8, &Ks[buf][flat * 8]);
      gload_lds16(Vswz + ((size_t)bh * 64 + row) * T_SEQ + kv0 + ch * 8, &Vs[buf][flat * 8]);
    }
  };

  // wave w owns q rows [q0 + w*64, +64): groups g=0,1 of 32 rows
  bf16x8_t qf[2][4];
  #pragma unroll
  for (int g = 0; g < 2; g++)
    #pragma unroll
    for (int ds = 0; ds < 4; ds++)
      qf[g][ds] = *(const bf16x8_t*)&Qb[(kvbase + q0 + w * 64 + g * 32 + q31) * 64 + ds * 16 + hi * 8];

  f32x16_t accO[2][2];
  #pragma unroll
  for (int g = 0; g < 2; g++)
    #pragma unroll
    for (int di = 0; di < 2; di++)
      #pragma unroll
      for (int j = 0; j < 16; j++) accO[g][di][j] = 0.f;
  float l_part[2] = {0.f, 0.f};

  stage(0, 0);
  __syncthreads();
  int cur = 0;

  for (int ti = 0; ti < nT; ++ti) {
    if (ti + 1 < nT) stage(cur ^ 1, (ti + 1) * 64);   // async prefetch during compute

    // wave 0 (rows q0..q0+63) is fully masked on the last tile
    const bool active = !(ti == nT - 1 && w == 0);    // wave-uniform branch
    if (active) {
      // ---- S^T = K · Q^T : each ka read feeds both q-groups ----
      f32x16_t sc[2][2];
      #pragma unroll
      for (int g = 0; g < 2; g++)
        #pragma unroll
        for (int c = 0; c < 2; c++)
          #pragma unroll
          for (int j = 0; j < 16; j++) sc[g][c][j] = 0.f;
      #pragma unroll
      for (int ds = 0; ds < 4; ds++)
        #pragma unroll
        for (int c = 0; c < 2; c++) {
          const int row = c * 32 + q31;
          bf16x8_t ka = *(const bf16x8_t*)&Ks[cur][row * 64 + (((ds * 2 + hi) ^ (row & 7)) << 3)];
          sc[0][c] = __builtin_amdgcn_mfma_f32_32x32x16_bf16(ka, qf[0][ds], sc[0][c], 0, 0, 0);
          sc[1][c] = __builtin_amdgcn_mfma_f32_32x32x16_bf16(ka, qf[1][ds], sc[1][c], 0, 0, 0);
        }

      // ---- causal mask: wave w's diagonal tile is nT-2+w ----
      if (ti == nT - 2 + w) {
        #pragma unroll
        for (int g = 0; g < 2; g++)
          #pragma unroll
          for (int c = 0; c < 2; c++)
            #pragma unroll
            for (int r = 0; r < 16; r++) {
              const int kvl = c * 32 + (r & 3) + 8 * (r >> 2) + 4 * hi;
              if (kvl > g * 32 + q31) sc[g][c][r] = -1e30f;
            }
      }

      // ---- P^T = exp2(S^T) in-register; PV with va shared across groups ----
      #pragma unroll
      for (int c = 0; c < 2; c++) {
        bf16x8_t pbA[2], pbB[2];
        #pragma unroll
        for (int g = 0; g < 2; g++) {
          float p[16];
          #pragma unroll
          for (int r = 0; r < 16; r++) {
            p[r] = fast_exp2(sc[g][c][r]);
            l_part[g] += p[r];
          }
          unsigned pk0 = cvtpk(p[0], p[1]),   pk1 = cvtpk(p[2], p[3]);
          unsigned pk2 = cvtpk(p[4], p[5]),   pk3 = cvtpk(p[6], p[7]);
          unsigned pk4 = cvtpk(p[8], p[9]),   pk5 = cvtpk(p[10], p[11]);
          unsigned pk6 = cvtpk(p[12], p[13]), pk7 = cvtpk(p[14], p[15]);
          PLSWAP(pk0, pk2); PLSWAP(pk1, pk3);
          PLSWAP(pk4, pk6); PLSWAP(pk5, pk7);
          union { unsigned u[4]; bf16x8_t v; } ua = {{pk0, pk1, pk2, pk3}};
          union { unsigned u[4]; bf16x8_t v; } ub = {{pk4, pk5, pk6, pk7}};
          pbA[g] = ua.v;
          pbB[g] = ub.v;
        }
        #pragma unroll
        for (int sl = 0; sl < 2; sl++) {
          const int s = c * 2 + sl;
          #pragma unroll
          for (int di = 0; di < 2; di++) {
            const int row = di * 32 + q31;
            bf16x8_t va = *(const bf16x8_t*)&Vs[cur][row * 64 + (((s * 2 + hi) ^ (row & 7)) << 3)];
            accO[0][di] = __builtin_amdgcn_mfma_f32_32x32x16_bf16(va, sl ? pbB[0] : pbA[0], accO[0][di], 0, 0, 0);
            accO[1][di] = __builtin_amdgcn_mfma_f32_32x32x16_bf16(va, sl ? pbB[1] : pbA[1], accO[1][di], 0, 0, 0);
          }
        }
      }
    }

    __syncthreads();   // implicit vmcnt(0) drain: prefetch complete; buffers swappable
    cur ^= 1;
  }

  // ---- epilogue per q-group ----
  #pragma unroll
  for (int g = 0; g < 2; g++) {
    const float l_tot = l_part[g] + __shfl_xor(l_part[g], 32);
    const float rl = 1.0f / l_tot;
    const int q = q0 + w * 64 + g * 32 + q31;
    unsigned short* orow = O + ((size_t)batch * T_SEQ + q) * CDIM + h * 64;
    #pragma unroll
    for (int di = 0; di < 2; di++)
      #pragma unroll
      for (int gg = 0; gg < 4; gg++) {
        const unsigned w0 = cvtpk(accO[g][di][4 * gg] * rl, accO[g][di][4 * gg + 1] * rl);
        const unsigned w1 = cvtpk(accO[g][di][4 * gg + 2] * rl, accO[g][di][4 * gg + 3] * rl);
        const int d = di * 32 + 8 * gg + 4 * hi;
        uint2 pr; pr.x = w0; pr.y = w1;
        *(uint2*)&orow[d] = pr;
      }
  }
}

extern "C" void kernel_launch(void* const* d_in, const int* in_sizes, int n_in,
                              void* d_out, int out_size, void* d_ws, size_t ws_size,
                              hipStream_t stream) {
  (void)in_sizes; (void)n_in; (void)out_size; (void)ws_size;
  const float* x      = (const float*)d_in[0];
  const float* w_qkv  = (const float*)d_in[1];
  const float* b_qkv  = (const float*)d_in[2];
  const float* w_proj = (const float*)d_in[3];
  const float* b_proj = (const float*)d_in[4];
  float* out = (float*)d_out;

  char* ws = (char*)d_ws;
  unsigned short* xb     = (unsigned short*)(ws);                       // 8 MB
  unsigned short* wqkvT  = (unsigned short*)(ws + ((size_t)8  << 20));  // 6 MB
  unsigned short* wprojT = (unsigned short*)(ws + ((size_t)14 << 20));  // 2 MB
  unsigned short* qb     = (unsigned short*)(ws + ((size_t)16 << 20));  // 8 MB
  unsigned short* kb     = (unsigned short*)(ws + ((size_t)24 << 20));  // 8 MB (swizzled)
  unsigned short* vtb    = (unsigned short*)(ws + ((size_t)32 << 20));  // 8 MB (swizzled)
  unsigned short* ab     = (unsigned short*)(ws + ((size_t)40 << 20));  // 8 MB

  conv_bf16_kernel<<<4096, 256, 0, stream>>>(x, xb, (2 * T_SEQ * CDIM) / 4);
  transpose_bf16_kernel<<<dim3(48, 16), 256, 0, stream>>>(w_qkv, wqkvT, 1024, 3072);
  transpose_bf16_kernel<<<dim3(16, 16), 256, 0, stream>>>(w_proj, wprojT, 1024, 1024);
  gemm_bt_kernel<0><<<dim3(24, 32), 256, 0, stream>>>(xb, wqkvT, b_qkv, qb, kb, vtb, nullptr);
  attn_kernel<<<512, 128, 0, stream>>>(qb, kb, vtb, ab);
  gemm_bt_kernel<1><<<dim3(16, 32), 256, 0, stream>>>(ab, wprojT, b_proj, nullptr, nullptr, nullptr, out);
}

// Round 13
// 95.523 us; speedup vs baseline: 1.2070x; 1.2070x over previous
//
#include <hip/hip_runtime.h>
#include <cstdint>

typedef __attribute__((ext_vector_type(8))) short bf16x8_t;
typedef __attribute__((ext_vector_type(4))) float f32x4_t;
typedef __attribute__((ext_vector_type(16))) float f32x16_t;

#define T_SEQ 2048
#define NHEAD 16
#define CDIM  1024

__device__ __forceinline__ unsigned short f2bf(float f) {
  union { float f; unsigned u; } v; v.f = f;
  unsigned r = v.u + 0x7FFFu + ((v.u >> 16) & 1u);
  return (unsigned short)(r >> 16);
}

__device__ __forceinline__ float fast_exp2(float x) {
#if __has_builtin(__builtin_amdgcn_exp2f)
  return __builtin_amdgcn_exp2f(x);
#else
  return __expf(x * 0.6931471805599453f);
#endif
}

// pack two f32 -> one u32 of 2 bf16 (RNE), src0 -> low half
__device__ __forceinline__ unsigned cvtpk(float lo, float hi) {
  unsigned r;
  asm("v_cvt_pk_bf16_f32 %0, %1, %2" : "=v"(r) : "v"(lo), "v"(hi));
  return r;
}
// a' = [a_lo ; b_lo], b' = [a_hi ; b_hi]  (v_permlane32_swap)
#define PLSWAP(a, b) asm("v_permlane32_swap_b32 %0, %1" : "+v"(a), "+v"(b))

__device__ __forceinline__ void gload_lds16(const void* g, void* l) {
  typedef const uint32_t __attribute__((address_space(1)))* gp_t;
  typedef uint32_t __attribute__((address_space(3)))* lp_t;
  __builtin_amdgcn_global_load_lds((gp_t)(uintptr_t)g, (lp_t)(uint32_t)(uintptr_t)l, 16, 0, 0);
}

// ---------------- fused prep: x->bf16 conv + both weight transposes ----------
// blocks 0..4095: conv (4096x256 float4)
// blocks 4096..4863: transpose w_qkv [1024][3072] -> [3072][1024] bf16
// blocks 4864..5119: transpose w_proj [1024][1024] -> [1024][1024] bf16
__global__ void prep_kernel(const float* __restrict__ x,
                            unsigned short* __restrict__ xb,
                            const float* __restrict__ w_qkv,
                            unsigned short* __restrict__ wqkvT,
                            const float* __restrict__ w_proj,
                            unsigned short* __restrict__ wprojT) {
  __shared__ unsigned short tile[64][65];
  const int b = blockIdx.x;
  const int t = threadIdx.x;
  if (b < 4096) {
    const int i = b * 256 + t;
    float4 v = ((const float4*)x)[i];
    ushort4 o;
    o.x = f2bf(v.x); o.y = f2bf(v.y); o.z = f2bf(v.z); o.w = f2bf(v.w);
    ((ushort4*)xb)[i] = o;
    return;
  }
  const float* W;
  unsigned short* WT;
  int c0, r0, C;
  if (b < 4864) {
    const int idx = b - 4096;
    W = w_qkv; WT = wqkvT; C = 3072;
    c0 = (idx % 48) * 64; r0 = (idx / 48) * 64;
  } else {
    const int idx = b - 4864;
    W = w_proj; WT = wprojT; C = 1024;
    c0 = (idx & 15) * 64; r0 = (idx >> 4) * 64;
  }
  #pragma unroll
  for (int i = 0; i < 16; i++) {
    int idx2 = i * 256 + t;
    int r = idx2 >> 6, c = idx2 & 63;
    tile[r][c] = f2bf(W[(size_t)(r0 + r) * C + c0 + c]);
  }
  __syncthreads();
  #pragma unroll
  for (int i = 0; i < 16; i++) {
    int idx2 = i * 256 + t;
    int c = idx2 >> 6, r = idx2 & 63;
    WT[(size_t)(c0 + c) * 1024 + r0 + r] = tile[r][c];
  }
}

// ---------------- QKV GEMM: 8-phase 256x256 template (best end-to-end, R11) --
__global__ __launch_bounds__(512)
void gemm_qkv_8ph(const unsigned short* __restrict__ A,
                  const unsigned short* __restrict__ Bt,
                  const float* __restrict__ bias,
                  unsigned short* __restrict__ q_out,
                  unsigned short* __restrict__ k_out,
                  unsigned short* __restrict__ v_out) {
  constexpr int K = 1024;
  const int t = threadIdx.x;
  const int wid = t >> 6, l = t & 63;
  const int wm = wid >> 2, wn = wid & 3;
  const int lr = l & 15, lg = l >> 4;

  const int b0 = blockIdx.x;
  const int wg = (b0 & 7) * 24 + (b0 >> 3);
  const int m0 = (wg / 12) * 256;
  const int n0 = (wg % 12) * 256;

  __shared__ __align__(16) unsigned short As[2][2][128 * 64];
  __shared__ __align__(16) unsigned short Bs[2][2][128 * 64];

  f32x4_t acc[8][4];
  #pragma unroll
  for (int mi = 0; mi < 8; mi++)
    #pragma unroll
    for (int ni = 0; ni < 4; ni++)
      acc[mi][ni] = (f32x4_t){0.f, 0.f, 0.f, 0.f};

  auto stgA = [&](int kt, int h) {
    const int slot = kt & 1;
    #pragma unroll
    for (int j = 0; j < 2; j++) {
      const int flat = j * 512 + t;
      const int row = flat >> 3, ch = flat & 7;
      gload_lds16(A + (size_t)(m0 + h * 128 + row) * K + kt * 64 + ((ch ^ (row & 7)) << 3),
                  &As[slot][h][flat * 8]);
    }
  };
  auto stgB = [&](int kt, int h) {
    const int slot = kt & 1;
    #pragma unroll
    for (int j = 0; j < 2; j++) {
      const int flat = j * 512 + t;
      const int row = flat >> 3, ch = flat & 7;
      gload_lds16(Bt + (size_t)(n0 + h * 128 + row) * K + kt * 64 + ((ch ^ (row & 7)) << 3),
                  &Bs[slot][h][flat * 8]);
    }
  };

  stgA(0, 0); stgA(0, 1); stgB(0, 0); stgB(0, 1);
  stgB(1, 0); stgB(1, 1);
  asm volatile("s_waitcnt vmcnt(4)" ::: "memory");
  __builtin_amdgcn_s_barrier();

  bf16x8_t bfrag[4][2];

  for (int it = 0; it < 8; ++it) {
    const bool more = (it < 7);
    const int tb = 2 * it + 1;
    #pragma unroll
    for (int half = 0; half < 2; ++half) {
      #pragma unroll
      for (int p = 0; p < 4; ++p) {
        bf16x8_t a[2][2];
        #pragma unroll
        for (int mm = 0; mm < 2; ++mm) {
          const int row = (2 * p + mm) * 16 + lr;
          #pragma unroll
          for (int ks = 0; ks < 2; ++ks)
            a[mm][ks] = *(const bf16x8_t*)&As[half][wm][row * 64 + (((ks * 4 + lg) ^ (lr & 7)) << 3)];
        }
        if (p == 0) {
          #pragma unroll
          for (int ni = 0; ni < 4; ++ni) {
            const int row = (wn & 1) * 64 + ni * 16 + lr;
            #pragma unroll
            for (int ks = 0; ks < 2; ++ks)
              bfrag[ni][ks] = *(const bf16x8_t*)&Bs[half][wn >> 1][row * 64 + (((ks * 4 + lg) ^ (lr & 7)) << 3)];
          }
        }
        if (half == 0) {
          if (p == 0)            { stgA(tb, 0); stgA(tb, 1); }
          else if (p == 1 && more) stgB(tb + 1, 0);
          else if (p == 2 && more) stgB(tb + 1, 1);
        } else {
          if (p == 0 && more)      stgA(tb + 1, 0);
          else if (p == 1 && more) stgA(tb + 1, 1);
          else if (p == 2 && more) stgB(tb + 2, 0);
          else if (p == 3 && more) stgB(tb + 2, 1);
        }
        __builtin_amdgcn_s_barrier();
        asm volatile("s_waitcnt lgkmcnt(0)" ::: "memory");
        __builtin_amdgcn_sched_barrier(0);
        __builtin_amdgcn_s_setprio(1);
        #pragma unroll
        for (int mm = 0; mm < 2; ++mm)
          #pragma unroll
          for (int ni = 0; ni < 4; ++ni)
            #pragma unroll
            for (int ks = 0; ks < 2; ++ks)
              acc[2 * p + mm][ni] =
                  __builtin_amdgcn_mfma_f32_16x16x32_bf16(a[mm][ks], bfrag[ni][ks],
                                                          acc[2 * p + mm][ni], 0, 0, 0);
        __builtin_amdgcn_s_setprio(0);
        if (p == 3) {
          if (half == 0) {
            if (more) asm volatile("s_waitcnt vmcnt(4)" ::: "memory");
            else      asm volatile("s_waitcnt vmcnt(0)" ::: "memory");
          } else if (more) {
            asm volatile("s_waitcnt vmcnt(4)" ::: "memory");
          }
        }
        __builtin_amdgcn_s_barrier();
      }
    }
  }

  const float QSCALE = 0.125f * 1.4426950408889634f;  // 1/sqrt(64) * log2(e)
  #pragma unroll
  for (int ni = 0; ni < 4; ++ni) {
    const int n = n0 + wn * 64 + ni * 16 + lr;
    const float bv = bias[n];
    const int s = n >> 10;           // 0:q 1:k 2:v
    const int hh = (n >> 6) & 15;
    const int d = n & 63;
    #pragma unroll
    for (int mi = 0; mi < 8; ++mi) {
      const int mbase = m0 + wm * 128 + mi * 16 + lg * 4;
      const int batch = mbase >> 11;
      const int tt = mbase & 2047;
      const int bhh = batch * NHEAD + hh;
      if (s == 0) {
        #pragma unroll
        for (int r = 0; r < 4; r++)
          q_out[((size_t)bhh * T_SEQ + tt + r) * 64 + d] = f2bf((acc[mi][ni][r] + bv) * QSCALE);
      } else if (s == 1) {
        #pragma unroll
        for (int r = 0; r < 4; r++) {
          const int dsw = ((((d >> 3) ^ ((tt + r) & 7)) << 3) | (d & 7));
          k_out[((size_t)bhh * T_SEQ + tt + r) * 64 + dsw] = f2bf(acc[mi][ni][r] + bv);
        }
      } else {
        ushort4 pk;
        pk.x = f2bf(acc[mi][ni][0] + bv);
        pk.y = f2bf(acc[mi][ni][1] + bv);
        pk.z = f2bf(acc[mi][ni][2] + bv);
        pk.w = f2bf(acc[mi][ni][3] + bv);
        const int c2 = (((tt >> 3) & 7) ^ (d & 7));
        const int tt2 = (tt & ~63) | (c2 << 3) | (tt & 7);
        *(ushort4*)&v_out[((size_t)bhh * 64 + d) * T_SEQ + tt2] = pk;
      }
    }
  }
}

// ---------------- proj GEMM: 2-phase 128x64, conflict-free swizzle -----------
__global__ void gemm_proj_kernel(const unsigned short* __restrict__ A,
                                 const unsigned short* __restrict__ Bt,
                                 const float* __restrict__ bias,
                                 float* __restrict__ c_out) {
  constexpr int K = 1024;
  const int t = threadIdx.x;
  const int w = t >> 6, l = t & 63;
  const int lr = l & 15, lg = l >> 4;
  const int wr = w >> 1, wc = w & 1;
  const int m0 = blockIdx.y * 128, n0 = blockIdx.x * 64;

  __shared__ __align__(16) unsigned short As[128 * 64];
  __shared__ __align__(16) unsigned short Bs[64 * 64];

  f32x4_t acc[4][2];
  #pragma unroll
  for (int mi = 0; mi < 4; mi++)
    #pragma unroll
    for (int ni = 0; ni < 2; ni++)
      acc[mi][ni] = (f32x4_t){0.f, 0.f, 0.f, 0.f};

  const int srow = t >> 3;
  const int sj   = t & 7;
  const int scol = (sj ^ (srow & 7)) * 8;
  const int ldst = srow * 64 + sj * 8;
  const size_t abase = (size_t)(m0 + srow) * K + scol;
  const size_t bbase = (size_t)(n0 + srow) * K + scol;

  for (int k0 = 0; k0 < K; k0 += 64) {
    __syncthreads();
    #pragma unroll
    for (int i = 0; i < 4; i++)
      gload_lds16(A + abase + (size_t)i * 32 * K + k0, &As[i * 32 * 64 + ldst]);
    #pragma unroll
    for (int i = 0; i < 2; i++)
      gload_lds16(Bt + bbase + (size_t)i * 32 * K + k0, &Bs[i * 32 * 64 + ldst]);
    __syncthreads();
    #pragma unroll
    for (int ks = 0; ks < 2; ks++) {
      bf16x8_t af[4], bfr[2];
      #pragma unroll
      for (int mi = 0; mi < 4; mi++) {
        const int row = wr * 64 + mi * 16 + lr;
        af[mi] = *(const bf16x8_t*)&As[row * 64 + (((ks * 4 + lg) ^ (row & 7)) << 3)];
      }
      #pragma unroll
      for (int ni = 0; ni < 2; ni++) {
        const int row = wc * 32 + ni * 16 + lr;
        bfr[ni] = *(const bf16x8_t*)&Bs[row * 64 + (((ks * 4 + lg) ^ (row & 7)) << 3)];
      }
      #pragma unroll
      for (int mi = 0; mi < 4; mi++)
        #pragma unroll
        for (int ni = 0; ni < 2; ni++)
          acc[mi][ni] = __builtin_amdgcn_mfma_f32_16x16x32_bf16(af[mi], bfr[ni], acc[mi][ni], 0, 0, 0);
    }
  }

  #pragma unroll
  for (int ni = 0; ni < 2; ni++) {
    const int n = n0 + wc * 32 + ni * 16 + lr;
    const float bv = bias[n];
    #pragma unroll
    for (int mi = 0; mi < 4; mi++) {
      const int m = m0 + wr * 64 + mi * 16 + lg * 4;
      #pragma unroll
      for (int r = 0; r < 4; r++)
        c_out[(size_t)(m + r) * 1024 + n] = acc[mi][ni][r] + bv;
    }
  }
}

// ---------------- causal flash attention v8 (proven best) --------------------
__global__ __launch_bounds__(256, 2)
void attn_kernel(const unsigned short* __restrict__ Qb,
                 const unsigned short* __restrict__ Kswz,
                 const unsigned short* __restrict__ Vswz,
                 unsigned short* __restrict__ O) {
  const int b0 = blockIdx.x;                 // 0..511
  const int xcd = b0 & 7;
  const int i = b0 >> 3;                     // 0..63 within xcd
  const int bh = xcd * 4 + (i & 3);          // 4 heads per XCD (L2 locality)
  const int strip = 15 - (i >> 2);           // heavy strips first
  const int batch = bh >> 4, h = bh & 15;
  const int q0 = strip * 128;
  const int nT = 2 * strip + 2;

  const int t = threadIdx.x;
  const int w = t >> 6, l = t & 63;
  const int q31 = l & 31, hi = l >> 5;

  __shared__ __align__(16) unsigned short Ks[2][64 * 64];
  __shared__ __align__(16) unsigned short Vs[2][64 * 64];

  const size_t kvbase = (size_t)bh * T_SEQ;

  auto stage = [&](int buf, int kv0) {
    #pragma unroll
    for (int i2 = 0; i2 < 2; i2++) {
      const int r0 = w * 16 + i2 * 8;
      gload_lds16(Kswz + (kvbase + kv0 + r0 + (l >> 3)) * 64 + (l & 7) * 8,
                  &Ks[buf][r0 * 64 + l * 8]);
      gload_lds16(Vswz + ((size_t)bh * 64 + r0 + (l >> 3)) * T_SEQ + kv0 + (l & 7) * 8,
                  &Vs[buf][r0 * 64 + l * 8]);
    }
  };

  bf16x8_t qf[4];
  #pragma unroll
  for (int ds = 0; ds < 4; ds++)
    qf[ds] = *(const bf16x8_t*)&Qb[(kvbase + q0 + w * 32 + q31) * 64 + ds * 16 + hi * 8];

  f32x16_t accO[2];
  #pragma unroll
  for (int di = 0; di < 2; di++)
    #pragma unroll
    for (int j = 0; j < 16; j++) accO[di][j] = 0.f;
  float l_part = 0.f;

  stage(0, 0);
  __syncthreads();
  int cur = 0;

  for (int ti = 0; ti < nT; ++ti) {
    if (ti + 1 < nT) stage(cur ^ 1, (ti + 1) * 64);   // async prefetch during compute

    const bool active = !(ti == nT - 1 && w < 2);     // last tile fully masked for w<2
    if (active) {
      f32x16_t sc[2];
      #pragma unroll
      for (int c = 0; c < 2; c++)
        #pragma unroll
        for (int j = 0; j < 16; j++) sc[c][j] = 0.f;
      #pragma unroll
      for (int ds = 0; ds < 4; ds++) {
        #pragma unroll
        for (int c = 0; c < 2; c++) {
          const int row = c * 32 + q31;
          bf16x8_t ka = *(const bf16x8_t*)&Ks[cur][row * 64 + (((ds * 2 + hi) ^ (row & 7)) << 3)];
          sc[c] = __builtin_amdgcn_mfma_f32_32x32x16_bf16(ka, qf[ds], sc[c], 0, 0, 0);
        }
      }

      if ((ti == nT - 2 && w < 2) || (ti == nT - 1 && w >= 2)) {
        const int lb = (ti == nT - 1) ? 64 : 0;
        const int ql = w * 32 + q31;
        #pragma unroll
        for (int c = 0; c < 2; c++)
          #pragma unroll
          for (int r = 0; r < 16; r++) {
            const int kvl = lb + c * 32 + (r & 3) + 8 * (r >> 2) + 4 * hi;
            if (kvl > ql) sc[c][r] = -1e30f;
          }
      }

      #pragma unroll
      for (int c = 0; c < 2; c++) {
        float p[16];
        #pragma unroll
        for (int r = 0; r < 16; r++) {
          p[r] = fast_exp2(sc[c][r]);
          l_part += p[r];
        }
        unsigned pk0 = cvtpk(p[0], p[1]),   pk1 = cvtpk(p[2], p[3]);
        unsigned pk2 = cvtpk(p[4], p[5]),   pk3 = cvtpk(p[6], p[7]);
        unsigned pk4 = cvtpk(p[8], p[9]),   pk5 = cvtpk(p[10], p[11]);
        unsigned pk6 = cvtpk(p[12], p[13]), pk7 = cvtpk(p[14], p[15]);

        PLSWAP(pk0, pk2);
        PLSWAP(pk1, pk3);
        union { unsigned u[4]; bf16x8_t v; } pb0 = {{pk0, pk1, pk2, pk3}};
        {
          const int s = c * 2;
          #pragma unroll
          for (int di = 0; di < 2; di++) {
            const int row = di * 32 + q31;
            bf16x8_t va = *(const bf16x8_t*)&Vs[cur][row * 64 + (((s * 2 + hi) ^ (row & 7)) << 3)];
            accO[di] = __builtin_amdgcn_mfma_f32_32x32x16_bf16(va, pb0.v, accO[di], 0, 0, 0);
          }
        }
        PLSWAP(pk4, pk6);
        PLSWAP(pk5, pk7);
        union { unsigned u[4]; bf16x8_t v; } pb1 = {{pk4, pk5, pk6, pk7}};
        {
          const int s = c * 2 + 1;
          #pragma unroll
          for (int di = 0; di < 2; di++) {
            const int row = di * 32 + q31;
            bf16x8_t va = *(const bf16x8_t*)&Vs[cur][row * 64 + (((s * 2 + hi) ^ (row & 7)) << 3)];
            accO[di] = __builtin_amdgcn_mfma_f32_32x32x16_bf16(va, pb1.v, accO[di], 0, 0, 0);
          }
        }
      }
    }

    __syncthreads();
    cur ^= 1;
  }

  const float l_tot = l_part + __shfl_xor(l_part, 32);
  const float rl = 1.0f / l_tot;
  const int q = q0 + w * 32 + q31;
  unsigned short* orow = O + ((size_t)batch * T_SEQ + q) * CDIM + h * 64;
  #pragma unroll
  for (int di = 0; di < 2; di++)
    #pragma unroll
    for (int g = 0; g < 4; g++) {
      const unsigned w0 = cvtpk(accO[di][4 * g] * rl, accO[di][4 * g + 1] * rl);
      const unsigned w1 = cvtpk(accO[di][4 * g + 2] * rl, accO[di][4 * g + 3] * rl);
      const int d = di * 32 + 8 * g + 4 * hi;
      uint2 pr; pr.x = w0; pr.y = w1;
      *(uint2*)&orow[d] = pr;
    }
}

extern "C" void kernel_launch(void* const* d_in, const int* in_sizes, int n_in,
                              void* d_out, int out_size, void* d_ws, size_t ws_size,
                              hipStream_t stream) {
  (void)in_sizes; (void)n_in; (void)out_size; (void)ws_size;
  const float* x      = (const float*)d_in[0];
  const float* w_qkv  = (const float*)d_in[1];
  const float* b_qkv  = (const float*)d_in[2];
  const float* w_proj = (const float*)d_in[3];
  const float* b_proj = (const float*)d_in[4];
  float* out = (float*)d_out;

  char* ws = (char*)d_ws;
  unsigned short* xb     = (unsigned short*)(ws);                       // 8 MB
  unsigned short* wqkvT  = (unsigned short*)(ws + ((size_t)8  << 20));  // 6 MB
  unsigned short* wprojT = (unsigned short*)(ws + ((size_t)14 << 20));  // 2 MB
  unsigned short* qb     = (unsigned short*)(ws + ((size_t)16 << 20));  // 8 MB
  unsigned short* kb     = (unsigned short*)(ws + ((size_t)24 << 20));  // 8 MB (swizzled)
  unsigned short* vtb    = (unsigned short*)(ws + ((size_t)32 << 20));  // 8 MB (swizzled)
  unsigned short* ab     = (unsigned short*)(ws + ((size_t)40 << 20));  // 8 MB

  prep_kernel<<<5120, 256, 0, stream>>>(x, xb, w_qkv, wqkvT, w_proj, wprojT);
  gemm_qkv_8ph<<<192, 512, 0, stream>>>(xb, wqkvT, b_qkv, qb, kb, vtb);
  attn_kernel<<<512, 256, 0, stream>>>(qb, kb, vtb, ab);
  gemm_proj_kernel<<<dim3(16, 32), 256, 0, stream>>>(ab, wprojT, b_proj, out);
}

// Round 14
// 92.796 us; speedup vs baseline: 1.2424x; 1.0294x over previous
//
#include <hip/hip_runtime.h>
#include <cstdint>

typedef __attribute__((ext_vector_type(8))) short bf16x8_t;
typedef __attribute__((ext_vector_type(4))) float f32x4_t;
typedef __attribute__((ext_vector_type(16))) float f32x16_t;

#define T_SEQ 2048
#define NHEAD 16
#define CDIM  1024

__device__ __forceinline__ unsigned short f2bf(float f) {
  union { float f; unsigned u; } v; v.f = f;
  unsigned r = v.u + 0x7FFFu + ((v.u >> 16) & 1u);
  return (unsigned short)(r >> 16);
}

__device__ __forceinline__ float fast_exp2(float x) {
#if __has_builtin(__builtin_amdgcn_exp2f)
  return __builtin_amdgcn_exp2f(x);
#else
  return __expf(x * 0.6931471805599453f);
#endif
}

// pack two f32 -> one u32 of 2 bf16 (RNE), src0 -> low half
__device__ __forceinline__ unsigned cvtpk(float lo, float hi) {
  unsigned r;
  asm("v_cvt_pk_bf16_f32 %0, %1, %2" : "=v"(r) : "v"(lo), "v"(hi));
  return r;
}
// a' = [a_lo ; b_lo], b' = [a_hi ; b_hi]  (v_permlane32_swap)
#define PLSWAP(a, b) asm("v_permlane32_swap_b32 %0, %1" : "+v"(a), "+v"(b))

__device__ __forceinline__ void gload_lds16(const void* g, void* l) {
  typedef const uint32_t __attribute__((address_space(1)))* gp_t;
  typedef uint32_t __attribute__((address_space(3)))* lp_t;
  __builtin_amdgcn_global_load_lds((gp_t)(uintptr_t)g, (lp_t)(uint32_t)(uintptr_t)l, 16, 0, 0);
}

// ---------------- fused prep: x->bf16 conv + both weight transposes ----------
__global__ void prep_kernel(const float* __restrict__ x,
                            unsigned short* __restrict__ xb,
                            const float* __restrict__ w_qkv,
                            unsigned short* __restrict__ wqkvT,
                            const float* __restrict__ w_proj,
                            unsigned short* __restrict__ wprojT) {
  __shared__ unsigned short tile[64][65];
  const int b = blockIdx.x;
  const int t = threadIdx.x;
  if (b < 4096) {
    const int i = b * 256 + t;
    float4 v = ((const float4*)x)[i];
    ushort4 o;
    o.x = f2bf(v.x); o.y = f2bf(v.y); o.z = f2bf(v.z); o.w = f2bf(v.w);
    ((ushort4*)xb)[i] = o;
    return;
  }
  const float* W;
  unsigned short* WT;
  int c0, r0, C;
  if (b < 4864) {
    const int idx = b - 4096;
    W = w_qkv; WT = wqkvT; C = 3072;
    c0 = (idx % 48) * 64; r0 = (idx / 48) * 64;
  } else {
    const int idx = b - 4864;
    W = w_proj; WT = wprojT; C = 1024;
    c0 = (idx & 15) * 64; r0 = (idx >> 4) * 64;
  }
  #pragma unroll
  for (int i = 0; i < 16; i++) {
    int idx2 = i * 256 + t;
    int r = idx2 >> 6, c = idx2 & 63;
    tile[r][c] = f2bf(W[(size_t)(r0 + r) * C + c0 + c]);
  }
  __syncthreads();
  #pragma unroll
  for (int i = 0; i < 16; i++) {
    int idx2 = i * 256 + t;
    int c = idx2 >> 6, r = idx2 & 63;
    WT[(size_t)(c0 + c) * 1024 + r0 + r] = tile[r][c];
  }
}

// ---------------- QKV GEMM: 8-phase 256x192 (grid = 256 = 1 block/CU) --------
// BM=256 BN=192 BK=64, 8 waves (2M x 4N), per-wave 128x48 (3 n-frags).
// LDS 112KB: As[slot][mhalf][128x64], Bs[slot][192x64]. Both-sides XOR swizzle.
// Per K-tile loads/thread: A = 4 (2 halves x 2), B = 3 (3 64-row units).
// Half-end waits vmcnt(3) = newest B group outstanding; everything older
// (incl. the tile about to be consumed) landed. Same FIFO invariant as R11.
__global__ __launch_bounds__(512)
void gemm_qkv_8ph(const unsigned short* __restrict__ A,
                  const unsigned short* __restrict__ Bt,
                  const float* __restrict__ bias,
                  unsigned short* __restrict__ q_out,
                  unsigned short* __restrict__ k_out,
                  unsigned short* __restrict__ v_out) {
  constexpr int K = 1024;
  const int t = threadIdx.x;
  const int wid = t >> 6, l = t & 63;
  const int wm = wid >> 2, wn = wid & 3;
  const int lr = l & 15, lg = l >> 4;

  // 256 blocks: bijective XCD swizzle; per XCD: 2 contiguous m-tiles (A-band
  // 512 rows = 1MB bf16, L2-resident), n fast-varying
  const int b0 = blockIdx.x;
  const int wg = (b0 & 7) * 32 + (b0 >> 3);
  const int m0 = (wg >> 4) * 256;
  const int n0 = (wg & 15) * 192;

  __shared__ __align__(16) unsigned short As[2][2][128 * 64];
  __shared__ __align__(16) unsigned short Bs[2][192 * 64];

  f32x4_t acc[8][3];
  #pragma unroll
  for (int mi = 0; mi < 8; mi++)
    #pragma unroll
    for (int ni = 0; ni < 3; ni++)
      acc[mi][ni] = (f32x4_t){0.f, 0.f, 0.f, 0.f};

  auto stgA = [&](int kt, int h) {
    const int slot = kt & 1;
    #pragma unroll
    for (int j = 0; j < 2; j++) {
      const int flat = j * 512 + t;
      const int row = flat >> 3, ch = flat & 7;
      gload_lds16(A + (size_t)(m0 + h * 128 + row) * K + kt * 64 + ((ch ^ (row & 7)) << 3),
                  &As[slot][h][flat * 8]);
    }
  };
  // one 64-row unit (8KB): rows u*64 .. u*64+63
  auto stgB = [&](int kt, int u) {
    const int slot = kt & 1;
    const int row = u * 64 + (t >> 3), ch = t & 7;
    gload_lds16(Bt + (size_t)(n0 + row) * K + kt * 64 + ((ch ^ (row & 7)) << 3),
                &Bs[slot][(size_t)u * 4096 + t * 8]);
  };

  // prologue: tile0 fully (A 4 + B 3 loads), tile1 B (3 loads)
  stgA(0, 0); stgA(0, 1);
  stgB(0, 0); stgB(0, 1); stgB(0, 2);
  stgB(1, 0); stgB(1, 1); stgB(1, 2);
  asm volatile("s_waitcnt vmcnt(3)" ::: "memory");   // tile0 landed (B1 may fly)
  __builtin_amdgcn_s_barrier();

  bf16x8_t bfrag[3][2];

  for (int it = 0; it < 8; ++it) {
    const bool more = (it < 7);
    const int tb = 2 * it + 1;
    #pragma unroll
    for (int half = 0; half < 2; ++half) {     // half == slot of consumed tile
      #pragma unroll
      for (int p = 0; p < 4; ++p) {
        bf16x8_t a[2][2];
        #pragma unroll
        for (int mm = 0; mm < 2; ++mm) {
          const int row = (2 * p + mm) * 16 + lr;
          #pragma unroll
          for (int ks = 0; ks < 2; ++ks)
            a[mm][ks] = *(const bf16x8_t*)&As[half][wm][row * 64 + (((ks * 4 + lg) ^ (lr & 7)) << 3)];
        }
        if (p == 0) {
          #pragma unroll
          for (int ni = 0; ni < 3; ++ni) {
            const int row = wn * 48 + ni * 16 + lr;
            #pragma unroll
            for (int ks = 0; ks < 2; ++ks)
              bfrag[ni][ks] = *(const bf16x8_t*)&Bs[half][row * 64 + (((ks * 4 + lg) ^ (lr & 7)) << 3)];
          }
        }
        // ---- stage issue (regions written only after their last read) ----
        if (half == 0) {
          if (p == 0)              { stgA(tb, 0); stgA(tb, 1); }
          else if (p == 1 && more) { stgB(tb + 1, 0); stgB(tb + 1, 1); }
          else if (p == 2 && more) { stgB(tb + 1, 2); }
        } else {
          if (p == 0 && more)      { stgA(tb + 1, 0); }
          else if (p == 1 && more) { stgA(tb + 1, 1); }
          else if (p == 2 && more) { stgB(tb + 2, 0); stgB(tb + 2, 1); }
          else if (p == 3 && more) { stgB(tb + 2, 2); }
        }
        __builtin_amdgcn_s_barrier();
        asm volatile("s_waitcnt lgkmcnt(0)" ::: "memory");
        __builtin_amdgcn_sched_barrier(0);
        __builtin_amdgcn_s_setprio(1);
        #pragma unroll
        for (int mm = 0; mm < 2; ++mm)
          #pragma unroll
          for (int ni = 0; ni < 3; ++ni)
            #pragma unroll
            for (int ks = 0; ks < 2; ++ks)
              acc[2 * p + mm][ni] =
                  __builtin_amdgcn_mfma_f32_16x16x32_bf16(a[mm][ks], bfrag[ni][ks],
                                                          acc[2 * p + mm][ni], 0, 0, 0);
        __builtin_amdgcn_s_setprio(0);
        if (p == 3) {                       // K-tile boundary waits (counted)
          if (half == 0) {
            if (more) asm volatile("s_waitcnt vmcnt(3)" ::: "memory");
            else      asm volatile("s_waitcnt vmcnt(0)" ::: "memory");
          } else if (more) {
            asm volatile("s_waitcnt vmcnt(3)" ::: "memory");
          }
        }
        __builtin_amdgcn_s_barrier();
      }
    }
  }

  // ---- QKV scatter epilogue (fragment bases 16-aligned -> s wave-uniform) ---
  const float QSCALE = 0.125f * 1.4426950408889634f;  // 1/sqrt(64) * log2(e)
  #pragma unroll
  for (int ni = 0; ni < 3; ++ni) {
    const int n = n0 + wn * 48 + ni * 16 + lr;
    const float bv = bias[n];
    const int s = n >> 10;           // 0:q 1:k 2:v
    const int hh = (n >> 6) & 15;
    const int d = n & 63;
    #pragma unroll
    for (int mi = 0; mi < 8; ++mi) {
      const int mbase = m0 + wm * 128 + mi * 16 + lg * 4;
      const int batch = mbase >> 11;
      const int tt = mbase & 2047;
      const int bhh = batch * NHEAD + hh;
      if (s == 0) {
        #pragma unroll
        for (int r = 0; r < 4; r++)
          q_out[((size_t)bhh * T_SEQ + tt + r) * 64 + d] = f2bf((acc[mi][ni][r] + bv) * QSCALE);
      } else if (s == 1) {
        #pragma unroll
        for (int r = 0; r < 4; r++) {
          const int dsw = ((((d >> 3) ^ ((tt + r) & 7)) << 3) | (d & 7));
          k_out[((size_t)bhh * T_SEQ + tt + r) * 64 + dsw] = f2bf(acc[mi][ni][r] + bv);
        }
      } else {
        ushort4 pk;
        pk.x = f2bf(acc[mi][ni][0] + bv);
        pk.y = f2bf(acc[mi][ni][1] + bv);
        pk.z = f2bf(acc[mi][ni][2] + bv);
        pk.w = f2bf(acc[mi][ni][3] + bv);
        const int c2 = (((tt >> 3) & 7) ^ (d & 7));
        const int tt2 = (tt & ~63) | (c2 << 3) | (tt & 7);
        *(ushort4*)&v_out[((size_t)bhh * 64 + d) * T_SEQ + tt2] = pk;
      }
    }
  }
}

// ---------------- proj GEMM: 2-phase 128x64, conflict-free swizzle -----------
__global__ void gemm_proj_kernel(const unsigned short* __restrict__ A,
                                 const unsigned short* __restrict__ Bt,
                                 const float* __restrict__ bias,
                                 float* __restrict__ c_out) {
  constexpr int K = 1024;
  const int t = threadIdx.x;
  const int w = t >> 6, l = t & 63;
  const int lr = l & 15, lg = l >> 4;
  const int wr = w >> 1, wc = w & 1;
  const int m0 = blockIdx.y * 128, n0 = blockIdx.x * 64;

  __shared__ __align__(16) unsigned short As[128 * 64];
  __shared__ __align__(16) unsigned short Bs[64 * 64];

  f32x4_t acc[4][2];
  #pragma unroll
  for (int mi = 0; mi < 4; mi++)
    #pragma unroll
    for (int ni = 0; ni < 2; ni++)
      acc[mi][ni] = (f32x4_t){0.f, 0.f, 0.f, 0.f};

  const int srow = t >> 3;
  const int sj   = t & 7;
  const int scol = (sj ^ (srow & 7)) * 8;
  const int ldst = srow * 64 + sj * 8;
  const size_t abase = (size_t)(m0 + srow) * K + scol;
  const size_t bbase = (size_t)(n0 + srow) * K + scol;

  for (int k0 = 0; k0 < K; k0 += 64) {
    __syncthreads();
    #pragma unroll
    for (int i = 0; i < 4; i++)
      gload_lds16(A + abase + (size_t)i * 32 * K + k0, &As[i * 32 * 64 + ldst]);
    #pragma unroll
    for (int i = 0; i < 2; i++)
      gload_lds16(Bt + bbase + (size_t)i * 32 * K + k0, &Bs[i * 32 * 64 + ldst]);
    __syncthreads();
    #pragma unroll
    for (int ks = 0; ks < 2; ks++) {
      bf16x8_t af[4], bfr[2];
      #pragma unroll
      for (int mi = 0; mi < 4; mi++) {
        const int row = wr * 64 + mi * 16 + lr;
        af[mi] = *(const bf16x8_t*)&As[row * 64 + (((ks * 4 + lg) ^ (row & 7)) << 3)];
      }
      #pragma unroll
      for (int ni = 0; ni < 2; ni++) {
        const int row = wc * 32 + ni * 16 + lr;
        bfr[ni] = *(const bf16x8_t*)&Bs[row * 64 + (((ks * 4 + lg) ^ (row & 7)) << 3)];
      }
      #pragma unroll
      for (int mi = 0; mi < 4; mi++)
        #pragma unroll
        for (int ni = 0; ni < 2; ni++)
          acc[mi][ni] = __builtin_amdgcn_mfma_f32_16x16x32_bf16(af[mi], bfr[ni], acc[mi][ni], 0, 0, 0);
    }
  }

  #pragma unroll
  for (int ni = 0; ni < 2; ni++) {
    const int n = n0 + wc * 32 + ni * 16 + lr;
    const float bv = bias[n];
    #pragma unroll
    for (int mi = 0; mi < 4; mi++) {
      const int m = m0 + wr * 64 + mi * 16 + lg * 4;
      #pragma unroll
      for (int r = 0; r < 4; r++)
        c_out[(size_t)(m + r) * 1024 + n] = acc[mi][ni][r] + bv;
    }
  }
}

// ---------------- causal flash attention v8 (proven best) --------------------
__global__ __launch_bounds__(256, 2)
void attn_kernel(const unsigned short* __restrict__ Qb,
                 const unsigned short* __restrict__ Kswz,
                 const unsigned short* __restrict__ Vswz,
                 unsigned short* __restrict__ O) {
  const int b0 = blockIdx.x;                 // 0..511
  const int xcd = b0 & 7;
  const int i = b0 >> 3;                     // 0..63 within xcd
  const int bh = xcd * 4 + (i & 3);          // 4 heads per XCD (L2 locality)
  const int strip = 15 - (i >> 2);           // heavy strips first
  const int batch = bh >> 4, h = bh & 15;
  const int q0 = strip * 128;
  const int nT = 2 * strip + 2;

  const int t = threadIdx.x;
  const int w = t >> 6, l = t & 63;
  const int q31 = l & 31, hi = l >> 5;

  __shared__ __align__(16) unsigned short Ks[2][64 * 64];
  __shared__ __align__(16) unsigned short Vs[2][64 * 64];

  const size_t kvbase = (size_t)bh * T_SEQ;

  auto stage = [&](int buf, int kv0) {
    #pragma unroll
    for (int i2 = 0; i2 < 2; i2++) {
      const int r0 = w * 16 + i2 * 8;
      gload_lds16(Kswz + (kvbase + kv0 + r0 + (l >> 3)) * 64 + (l & 7) * 8,
                  &Ks[buf][r0 * 64 + l * 8]);
      gload_lds16(Vswz + ((size_t)bh * 64 + r0 + (l >> 3)) * T_SEQ + kv0 + (l & 7) * 8,
                  &Vs[buf][r0 * 64 + l * 8]);
    }
  };

  bf16x8_t qf[4];
  #pragma unroll
  for (int ds = 0; ds < 4; ds++)
    qf[ds] = *(const bf16x8_t*)&Qb[(kvbase + q0 + w * 32 + q31) * 64 + ds * 16 + hi * 8];

  f32x16_t accO[2];
  #pragma unroll
  for (int di = 0; di < 2; di++)
    #pragma unroll
    for (int j = 0; j < 16; j++) accO[di][j] = 0.f;
  float l_part = 0.f;

  stage(0, 0);
  __syncthreads();
  int cur = 0;

  for (int ti = 0; ti < nT; ++ti) {
    if (ti + 1 < nT) stage(cur ^ 1, (ti + 1) * 64);   // async prefetch during compute

    const bool active = !(ti == nT - 1 && w < 2);     // last tile fully masked for w<2
    if (active) {
      f32x16_t sc[2];
      #pragma unroll
      for (int c = 0; c < 2; c++)
        #pragma unroll
        for (int j = 0; j < 16; j++) sc[c][j] = 0.f;
      #pragma unroll
      for (int ds = 0; ds < 4; ds++) {
        #pragma unroll
        for (int c = 0; c < 2; c++) {
          const int row = c * 32 + q31;
          bf16x8_t ka = *(const bf16x8_t*)&Ks[cur][row * 64 + (((ds * 2 + hi) ^ (row & 7)) << 3)];
          sc[c] = __builtin_amdgcn_mfma_f32_32x32x16_bf16(ka, qf[ds], sc[c], 0, 0, 0);
        }
      }

      if ((ti == nT - 2 && w < 2) || (ti == nT - 1 && w >= 2)) {
        const int lb = (ti == nT - 1) ? 64 : 0;
        const int ql = w * 32 + q31;
        #pragma unroll
        for (int c = 0; c < 2; c++)
          #pragma unroll
          for (int r = 0; r < 16; r++) {
            const int kvl = lb + c * 32 + (r & 3) + 8 * (r >> 2) + 4 * hi;
            if (kvl > ql) sc[c][r] = -1e30f;
          }
      }

      #pragma unroll
      for (int c = 0; c < 2; c++) {
        float p[16];
        #pragma unroll
        for (int r = 0; r < 16; r++) {
          p[r] = fast_exp2(sc[c][r]);
          l_part += p[r];
        }
        unsigned pk0 = cvtpk(p[0], p[1]),   pk1 = cvtpk(p[2], p[3]);
        unsigned pk2 = cvtpk(p[4], p[5]),   pk3 = cvtpk(p[6], p[7]);
        unsigned pk4 = cvtpk(p[8], p[9]),   pk5 = cvtpk(p[10], p[11]);
        unsigned pk6 = cvtpk(p[12], p[13]), pk7 = cvtpk(p[14], p[15]);

        PLSWAP(pk0, pk2);
        PLSWAP(pk1, pk3);
        union { unsigned u[4]; bf16x8_t v; } pb0 = {{pk0, pk1, pk2, pk3}};
        {
          const int s = c * 2;
          #pragma unroll
          for (int di = 0; di < 2; di++) {
            const int row = di * 32 + q31;
            bf16x8_t va = *(const bf16x8_t*)&Vs[cur][row * 64 + (((s * 2 + hi) ^ (row & 7)) << 3)];
            accO[di] = __builtin_amdgcn_mfma_f32_32x32x16_bf16(va, pb0.v, accO[di], 0, 0, 0);
          }
        }
        PLSWAP(pk4, pk6);
        PLSWAP(pk5, pk7);
        union { unsigned u[4]; bf16x8_t v; } pb1 = {{pk4, pk5, pk6, pk7}};
        {
          const int s = c * 2 + 1;
          #pragma unroll
          for (int di = 0; di < 2; di++) {
            const int row = di * 32 + q31;
            bf16x8_t va = *(const bf16x8_t*)&Vs[cur][row * 64 + (((s * 2 + hi) ^ (row & 7)) << 3)];
            accO[di] = __builtin_amdgcn_mfma_f32_32x32x16_bf16(va, pb1.v, accO[di], 0, 0, 0);
          }
        }
      }
    }

    __syncthreads();
    cur ^= 1;
  }

  const float l_tot = l_part + __shfl_xor(l_part, 32);
  const float rl = 1.0f / l_tot;
  const int q = q0 + w * 32 + q31;
  unsigned short* orow = O + ((size_t)batch * T_SEQ + q) * CDIM + h * 64;
  #pragma unroll
  for (int di = 0; di < 2; di++)
    #pragma unroll
    for (int g = 0; g < 4; g++) {
      const unsigned w0 = cvtpk(accO[di][4 * g] * rl, accO[di][4 * g + 1] * rl);
      const unsigned w1 = cvtpk(accO[di][4 * g + 2] * rl, accO[di][4 * g + 3] * rl);
      const int d = di * 32 + 8 * g + 4 * hi;
      uint2 pr; pr.x = w0; pr.y = w1;
      *(uint2*)&orow[d] = pr;
    }
}

extern "C" void kernel_launch(void* const* d_in, const int* in_sizes, int n_in,
                              void* d_out, int out_size, void* d_ws, size_t ws_size,
                              hipStream_t stream) {
  (void)in_sizes; (void)n_in; (void)out_size; (void)ws_size;
  const float* x      = (const float*)d_in[0];
  const float* w_qkv  = (const float*)d_in[1];
  const float* b_qkv  = (const float*)d_in[2];
  const float* w_proj = (const float*)d_in[3];
  const float* b_proj = (const float*)d_in[4];
  float* out = (float*)d_out;

  char* ws = (char*)d_ws;
  unsigned short* xb     = (unsigned short*)(ws);                       // 8 MB
  unsigned short* wqkvT  = (unsigned short*)(ws + ((size_t)8  << 20));  // 6 MB
  unsigned short* wprojT = (unsigned short*)(ws + ((size_t)14 << 20));  // 2 MB
  unsigned short* qb     = (unsigned short*)(ws + ((size_t)16 << 20));  // 8 MB
  unsigned short* kb     = (unsigned short*)(ws + ((size_t)24 << 20));  // 8 MB (swizzled)
  unsigned short* vtb    = (unsigned short*)(ws + ((size_t)32 << 20));  // 8 MB (swizzled)
  unsigned short* ab     = (unsigned short*)(ws + ((size_t)40 << 20));  // 8 MB

  prep_kernel<<<5120, 256, 0, stream>>>(x, xb, w_qkv, wqkvT, w_proj, wprojT);
  gemm_qkv_8ph<<<256, 512, 0, stream>>>(xb, wqkvT, b_qkv, qb, kb, vtb);
  attn_kernel<<<512, 256, 0, stream>>>(qb, kb, vtb, ab);
  gemm_proj_kernel<<<dim3(16, 32), 256, 0, stream>>>(ab, wprojT, b_proj, out);
}